// Round 5
// baseline (731.728 us; speedup 1.0000x reference)
//
#include <hip/hip_runtime.h>
#include <hip/hip_bf16.h>

#define HW 128
#define NPIX 16384          // 128*128
#define CDEP 512
#define NB 8

typedef __attribute__((ext_vector_type(8))) short short8;
typedef __attribute__((ext_vector_type(8))) __bf16 bf16x8;
typedef __attribute__((ext_vector_type(4))) float f32x4;
typedef __attribute__((ext_vector_type(4))) unsigned int u32x4;

static __device__ inline bf16x8 asbf(short8 v) {
  union { short8 s; bf16x8 b; } u; u.s = v; return u.b;
}
// round-to-nearest-even f32 -> bf16 bits
static __device__ inline unsigned short f2bf(float x) {
  unsigned u = __float_as_uint(x);
  return (unsigned short)((u + 0x7fffu + ((u >> 16) & 1u)) >> 16);
}
static __device__ inline unsigned pk2(float lo, float hi) {
  return (unsigned)f2bf(lo) | ((unsigned)f2bf(hi) << 16);
}

// ---------------- tar normalize: [16384,512] f32 -> bf16 [p,C]; also zero the zero-page ----
__global__ __launch_bounds__(256) void k_norm_tar(const float* __restrict__ ft,
                                                  unsigned short* __restrict__ T,
                                                  float* __restrict__ zp) {
  if (blockIdx.x == 0 && threadIdx.x < 64)
    ((f32x4*)zp)[threadIdx.x] = (f32x4){0.f, 0.f, 0.f, 0.f};
  int wave = threadIdx.x >> 6, lane = threadIdx.x & 63;
  int p = blockIdx.x * 4 + wave;
  const float* row = ft + (size_t)p * CDEP + lane * 8;
  float4 v0 = *(const float4*)(row);
  float4 v1 = *(const float4*)(row + 4);
  float s = v0.x*v0.x + v0.y*v0.y + v0.z*v0.z + v0.w*v0.w
          + v1.x*v1.x + v1.y*v1.y + v1.z*v1.z + v1.w*v1.w;
  #pragma unroll
  for (int off = 1; off < 64; off <<= 1) s += __shfl_xor(s, off);
  float sc = 1.0f / fmaxf(sqrtf(s), 1e-12f);
  float vv[8] = {v0.x, v0.y, v0.z, v0.w, v1.x, v1.y, v1.z, v1.w};
  short8 pkv;
  #pragma unroll
  for (int i = 0; i < 8; ++i) pkv[i] = (short)f2bf(vv[i] * sc);
  *(short8*)(T + (size_t)p * CDEP + lane * 8) = pkv;
}

// -------- fully fused: raw f32 refs -> bf16 LDS staging -> MFMA -> invnorm -> softmax --------
// grid 2048 (XCD=batch swizzle); block 256 = 4 waves; WG: 8x8 out px, 16x16 q window.
// K = 512 in 8 chunks of 64 c; LDS staging layout (R1/R4-verified):
//   byte(q, c') = buf + q*128 + (((c'>>3) ^ (q&7))<<4) + (c'&7)*2
// Staging: lane=(y,x4) loads float4 row-segments (16x64B per wave instr);
//   c-range rotated by y (rot=(wave+y)&3), slot order flipped by x-parity -> 32-bank writes.
__global__ __launch_bounds__(256, 2) void k_fused(const unsigned short* __restrict__ Tb,
                                                  const float* __restrict__ fr,
                                                  const float* __restrict__ zp,
                                                  float* __restrict__ out) {
  __shared__ __align__(16) unsigned char lds[70656];
  // [0,65536): 2x32KB staging (epilogue reuses [0,37888) for S)
  // [65536,69632): ssq_part f32[4][256] ; [69632,70656): inv f32[256]
  const int t = threadIdx.x, lane = t & 63, wave = t >> 6;
  const int lb = blockIdx.x;
  const int logical = (lb & 7) * 256 + (lb >> 3);     // bijective: XCD <-> batch
  const int bx = logical & 15, by = (logical >> 4) & 15, bz = logical >> 8;
  const int wy = wave >> 1, wx = wave & 1;
  const int mA = lane & 15, kg = lane >> 4;

  // ---- staging geometry ----
  const int sy = lane >> 2, sx4 = lane & 3, x4b = sx4 & 1;
  const int rot = (wave + sy) & 3;
  const int gy = by * 8 - 4 + sy;
  const int gx4 = bx * 8 - 4 + sx4 * 4;
  const bool valid = ((unsigned)gy < 128u) && ((unsigned)gx4 <= 124u);
  const float* base = valid ? (fr + (size_t)bz * CDEP * NPIX + gy * HW + gx4) : zp;
  const size_t cstep = valid ? (size_t)NPIX : 0;
  const float* basec = base + (size_t)rot * 16 * cstep;   // fold rot into base

  // write addrs: q = sy*16 + sx4*4 + j ; slotidx = rot*2 + (si^x4b)
  int waddr[4][2];
  #pragma unroll
  for (int j = 0; j < 4; ++j) {
    int q = sy * 16 + sx4 * 4 + j, key = q & 7;
    #pragma unroll
    for (int si = 0; si < 2; ++si) {
      int s = si ^ x4b;
      waddr[j][si] = q * 128 + (((rot * 2 + s) ^ key) << 4);
    }
  }

  // ---- B-read offsets (R1-verified): byte = q*128 + ((kg^(q&7))<<4), step flips bit6 ----
  int qoff[9];
  #pragma unroll
  for (int tt = 0; tt < 9; ++tt) {
    int idx = tt * 16 + mA;
    int q = (wy * 4 + idx / 12) * 16 + (wx * 4 + idx % 12);
    qoff[tt] = q * 128 + ((kg << 4) ^ ((q & 7) << 4));
  }

  // ---- A fragments fully in registers ----
  const int py = by * 8 + wy * 4 + (mA >> 2), px = bx * 8 + wx * 4 + (mA & 3);
  const short* arow = (const short*)Tb + (size_t)(py * HW + px) * CDEP + kg * 8;
  short8 a[16];
  #pragma unroll
  for (int kk = 0; kk < 16; ++kk) a[kk] = *(const short8*)(arow + kk * 32);

  f32x4 acc[9];
  #pragma unroll
  for (int tt = 0; tt < 9; ++tt) acc[tt] = (f32x4){0.f, 0.f, 0.f, 0.f};
  float sq[4] = {0.f, 0.f, 0.f, 0.f};
  f32x4 v[16];

#define ISSUE(CH) { \
  _Pragma("unroll") \
  for (int cc = 0; cc < 16; ++cc) \
    v[cc] = *(const f32x4*)(basec + (size_t)((CH) * 64 + cc) * cstep); }

#define STAGEW(BUFO) { \
  _Pragma("unroll") \
  for (int j = 0; j < 4; ++j) { \
    _Pragma("unroll") \
    for (int si = 0; si < 2; ++si) { \
      int s = si ^ x4b; \
      u32x4 d; \
      _Pragma("unroll") \
      for (int k = 0; k < 4; ++k) { \
        float lo = v[s*8 + 2*k][j], hi = v[s*8 + 2*k + 1][j]; \
        sq[j] += lo*lo + hi*hi; \
        d[k] = pk2(lo, hi); \
      } \
      *(u32x4*)(lds + (BUFO) + waddr[j][si]) = d; \
    } } }

  // ---- prologue: stage chunk 0 -> buf0 ----
  ISSUE(0);
  STAGEW(0);
  __syncthreads();

  // ---- main loop: 8 chunks of 64 c, double-buffered ----
  #pragma unroll
  for (int ch = 0; ch < 8; ++ch) {
    if (ch < 7) ISSUE(ch + 1);           // T14: issue next chunk's loads early
    const int bufo = (ch & 1) << 15;
    __builtin_amdgcn_s_setprio(1);
    #pragma unroll
    for (int step = 0; step < 2; ++step) {
      bf16x8 af = asbf(a[ch * 2 + step]);
      const int sx = step << 6;
      #pragma unroll
      for (int tt = 0; tt < 9; ++tt) {
        short8 bv = *(const short8*)(lds + bufo + (qoff[tt] ^ sx));
        acc[tt] = __builtin_amdgcn_mfma_f32_16x16x32_bf16(af, asbf(bv), acc[tt], 0, 0, 0);
      }
    }
    __builtin_amdgcn_s_setprio(0);
    if (ch < 7) {
      const int nbufo = ((ch + 1) & 1) << 15;
      STAGEW(nbufo);
    }
    __syncthreads();
  }

  // ---- epilogue: ssq reduce + S spill + invnorm + softmax ----
  float* ssq_part = (float*)(lds + 65536);     // [4][256]
  #pragma unroll
  for (int j = 0; j < 4; ++j)
    ssq_part[wave * 256 + sy * 16 + sx4 * 4 + j] = sq[j];

  const int SSTR = 148;
  float* S = (float*)lds + wave * 16 * SSTR;   // 4 x 16 x 148 x 4B = 37888 B
  #pragma unroll
  for (int tt = 0; tt < 9; ++tt) {
    #pragma unroll
    for (int r = 0; r < 4; ++r)
      S[(kg * 4 + r) * SSTR + tt * 16 + mA] = acc[tt][r];
  }
  __syncthreads();

  float* inv_lds = (float*)(lds + 69632);      // [256]
  {
    float s = ssq_part[t] + ssq_part[256 + t] + ssq_part[512 + t] + ssq_part[768 + t];
    inv_lds[t] = 1.0f / fmaxf(sqrtf(s), 1e-12f);
  }
  __syncthreads();

  // softmax: 4 lanes per pixel over 81 window values (norm applied here)
  const int mrow = lane >> 2, s4 = lane & 3;
  const int myy = mrow >> 2, mxx = mrow & 3;
  const float* Srow = S + mrow * SSTR;
  float vals[21];
  float mx = -3.0e38f;
  #pragma unroll
  for (int i = 0; i < 21; ++i) {
    int j = s4 + 4 * i;
    if (j < 81) {
      int dy = j / 9, dx = j % 9;
      int qw = (wy * 4 + myy + dy) * 16 + wx * 4 + mxx + dx;
      float val = Srow[(myy + dy) * 12 + (mxx + dx)] * inv_lds[qw];
      vals[i] = val;
      mx = fmaxf(mx, val);
    }
  }
  mx = fmaxf(mx, __shfl_xor(mx, 1));
  mx = fmaxf(mx, __shfl_xor(mx, 2));
  float sum = 0.f;
  #pragma unroll
  for (int i = 0; i < 21; ++i) {
    int j = s4 + 4 * i;
    if (j < 81) { float e = __expf(vals[i] - mx); vals[i] = e; sum += e; }
  }
  sum += __shfl_xor(sum, 1);
  sum += __shfl_xor(sum, 2);
  float rs = 1.0f / sum;
  const int pg = (by * 8 + wy * 4 + myy) * HW + (bx * 8 + wx * 4 + mxx);
  float* op = out + ((size_t)bz * NPIX + pg) * 81;
  #pragma unroll
  for (int i = 0; i < 21; ++i) {
    int j = s4 + 4 * i;
    if (j < 81) op[j] = vals[i] * rs;
  }
#undef ISSUE
#undef STAGEW
}

extern "C" void kernel_launch(void* const* d_in, const int* in_sizes, int n_in,
                              void* d_out, int out_size, void* d_ws, size_t ws_size,
                              hipStream_t stream) {
  const float* ft = (const float*)d_in[0];
  const float* fr = (const float*)d_in[1];
  float* out = (float*)d_out;

  unsigned short* T = (unsigned short*)d_ws;                    // 16 MB bf16 tar
  float* zp = (float*)((char*)d_ws + (size_t)NPIX * CDEP * 2);  // 1 KB zero page

  k_norm_tar<<<dim3(NPIX / 4), dim3(256), 0, stream>>>(ft, T, zp);
  k_fused<<<dim3(2048), dim3(256), 0, stream>>>(T, fr, zp, out);
}

// Round 6
// 199.207 us; speedup vs baseline: 3.6732x; 3.6732x over previous
//
#include <hip/hip_runtime.h>
#include <hip/hip_bf16.h>

#define HW 128
#define NPIX 16384          // 128*128
#define CDEP 512
#define NB 8

typedef __attribute__((ext_vector_type(8))) short short8;
typedef __attribute__((ext_vector_type(8))) __bf16 bf16x8;
typedef __attribute__((ext_vector_type(4))) float f32x4;
typedef __attribute__((ext_vector_type(4))) unsigned int u32x4;

static __device__ inline bf16x8 asbf(short8 v) {
  union { short8 s; bf16x8 b; } u; u.s = v; return u.b;
}
// round-to-nearest-even f32 -> bf16 bits
static __device__ inline unsigned short f2bf(float x) {
  unsigned u = __float_as_uint(x);
  return (unsigned short)((u + 0x7fffu + ((u >> 16) & 1u)) >> 16);
}
static __device__ inline unsigned pk2(float lo, float hi) {
  return (unsigned)f2bf(lo) | ((unsigned)f2bf(hi) << 16);
}

// ---------------- tar normalize: [16384,512] f32 -> bf16 [p,C]; also zero the zero-page ----
__global__ __launch_bounds__(256) void k_norm_tar(const float* __restrict__ ft,
                                                  unsigned short* __restrict__ T,
                                                  float* __restrict__ zp) {
  if (blockIdx.x == 0 && threadIdx.x < 64)
    ((f32x4*)zp)[threadIdx.x] = (f32x4){0.f, 0.f, 0.f, 0.f};
  int wave = threadIdx.x >> 6, lane = threadIdx.x & 63;
  int p = blockIdx.x * 4 + wave;
  const float* row = ft + (size_t)p * CDEP + lane * 8;
  float4 v0 = *(const float4*)(row);
  float4 v1 = *(const float4*)(row + 4);
  float s = v0.x*v0.x + v0.y*v0.y + v0.z*v0.z + v0.w*v0.w
          + v1.x*v1.x + v1.y*v1.y + v1.z*v1.z + v1.w*v1.w;
  #pragma unroll
  for (int off = 1; off < 64; off <<= 1) s += __shfl_xor(s, off);
  float sc = 1.0f / fmaxf(sqrtf(s), 1e-12f);
  float vv[8] = {v0.x, v0.y, v0.z, v0.w, v1.x, v1.y, v1.z, v1.w};
  short8 pkv;
  #pragma unroll
  for (int i = 0; i < 8; ++i) pkv[i] = (short)f2bf(vv[i] * sc);
  *(short8*)(T + (size_t)p * CDEP + lane * 8) = pkv;
}

// -------- fully fused: raw f32 refs -> bf16 LDS staging -> MFMA -> invnorm -> softmax --------
// grid 2048 (XCD=batch swizzle); block 256 = 4 waves; WG: 8x8 out px, 16x16 q window.
// K = 512 in 8 chunks of 64 c; LDS staging layout (R1/R4-verified):
//   byte(q, c') = buf + q*128 + (((c'>>3) ^ (q&7))<<4) + (c'&7)*2
// Thread (wave, sy=lane>>2, sx4=lane&3) loads float4 row-segments at
//   c = ch*64 + rot*16 + cc (rot=(wave+sy)&3) -> ALL indices compile-time (no scratch).
__global__ __launch_bounds__(256, 2) void k_fused(const unsigned short* __restrict__ Tb,
                                                  const float* __restrict__ fr,
                                                  const float* __restrict__ zp,
                                                  float* __restrict__ out) {
  __shared__ __align__(16) unsigned char lds[70656];
  // [0,65536): 2x32KB staging; epilogue: S at [0,37888), probs at [38912,59648),
  // ssq_part at [65536,69632), inv at [69632,70656).
  const int t = threadIdx.x, lane = t & 63, wave = t >> 6;
  const int lb = blockIdx.x;
  const int logical = (lb & 7) * 256 + (lb >> 3);     // bijective: XCD <-> batch
  const int bx = logical & 15, by = (logical >> 4) & 15, bz = logical >> 8;
  const int wy = wave >> 1, wx = wave & 1;
  const int mA = lane & 15, kg = lane >> 4;

  // ---- staging geometry ----
  const int sy = lane >> 2, sx4 = lane & 3;
  const int rot = (wave + sy) & 3;
  const int gy = by * 8 - 4 + sy;
  const int gx4 = bx * 8 - 4 + sx4 * 4;
  const bool valid = ((unsigned)gy < 128u) && ((unsigned)gx4 <= 124u);
  const float* base = valid ? (fr + (size_t)bz * CDEP * NPIX + gy * HW + gx4) : zp;
  const size_t cstep = valid ? (size_t)NPIX : 0;
  const float* basec = base + (size_t)rot * 16 * cstep;   // fold rot into base

  // write addrs: q = sy*16 + sx4*4 + j ; slot = rot*2 + si (si static)
  int waddr[4][2];
  #pragma unroll
  for (int j = 0; j < 4; ++j) {
    int q = sy * 16 + sx4 * 4 + j, key = q & 7;
    #pragma unroll
    for (int si = 0; si < 2; ++si)
      waddr[j][si] = q * 128 + (((rot * 2 + si) ^ key) << 4);
  }

  // ---- B-read offsets (R1-verified): byte = q*128 + ((kg^(q&7))<<4), step flips bit6 ----
  int qoff[9];
  #pragma unroll
  for (int tt = 0; tt < 9; ++tt) {
    int idx = tt * 16 + mA;
    int q = (wy * 4 + idx / 12) * 16 + (wx * 4 + idx % 12);
    qoff[tt] = q * 128 + ((kg << 4) ^ ((q & 7) << 4));
  }

  // ---- A fragments fully in registers ----
  const int py = by * 8 + wy * 4 + (mA >> 2), px = bx * 8 + wx * 4 + (mA & 3);
  const short* arow = (const short*)Tb + (size_t)(py * HW + px) * CDEP + kg * 8;
  short8 a[16];
  #pragma unroll
  for (int kk = 0; kk < 16; ++kk) a[kk] = *(const short8*)(arow + kk * 32);

  f32x4 acc[9];
  #pragma unroll
  for (int tt = 0; tt < 9; ++tt) acc[tt] = (f32x4){0.f, 0.f, 0.f, 0.f};
  float sq[4] = {0.f, 0.f, 0.f, 0.f};
  f32x4 v[16];

#define ISSUE(CH) { \
  _Pragma("unroll") \
  for (int cc = 0; cc < 16; ++cc) \
    v[cc] = *(const f32x4*)(basec + (size_t)((CH) * 64 + cc) * cstep); }

#define STAGEW(BUFO) { \
  _Pragma("unroll") \
  for (int j = 0; j < 4; ++j) { \
    _Pragma("unroll") \
    for (int si = 0; si < 2; ++si) { \
      u32x4 d; \
      _Pragma("unroll") \
      for (int k = 0; k < 4; ++k) { \
        float lo = v[si*8 + 2*k][j], hi = v[si*8 + 2*k + 1][j]; \
        sq[j] += lo*lo + hi*hi; \
        d[k] = pk2(lo, hi); \
      } \
      *(u32x4*)(lds + (BUFO) + waddr[j][si]) = d; \
    } } }

  // ---- prologue: stage chunk 0 -> buf0 ----
  ISSUE(0);
  STAGEW(0);
  __syncthreads();

  // ---- main loop: 8 chunks of 64 c, double-buffered ----
  #pragma unroll
  for (int ch = 0; ch < 8; ++ch) {
    if (ch < 7) ISSUE(ch + 1);           // T14: issue next chunk's loads early
    const int bufo = (ch & 1) << 15;
    __builtin_amdgcn_s_setprio(1);
    #pragma unroll
    for (int step = 0; step < 2; ++step) {
      bf16x8 af = asbf(a[ch * 2 + step]);
      const int sx = step << 6;
      #pragma unroll
      for (int tt = 0; tt < 9; ++tt) {
        short8 bv = *(const short8*)(lds + bufo + (qoff[tt] ^ sx));
        acc[tt] = __builtin_amdgcn_mfma_f32_16x16x32_bf16(af, asbf(bv), acc[tt], 0, 0, 0);
      }
    }
    __builtin_amdgcn_s_setprio(0);
    if (ch < 7) {
      const int nbufo = ((ch + 1) & 1) << 15;
      STAGEW(nbufo);
    }
    __syncthreads();
  }

  // ---- epilogue: ssq partials + S spill + invnorm ----
  float* ssq_part = (float*)(lds + 65536);     // [4][256]
  #pragma unroll
  for (int j = 0; j < 4; ++j)
    ssq_part[wave * 256 + sy * 16 + sx4 * 4 + j] = sq[j];

  const int SSTR = 148;
  float* S = (float*)lds + wave * 16 * SSTR;   // 4 x 16 x 148 x 4B = 37888 B
  #pragma unroll
  for (int tt = 0; tt < 9; ++tt) {
    #pragma unroll
    for (int r = 0; r < 4; ++r)
      S[(kg * 4 + r) * SSTR + tt * 16 + mA] = acc[tt][r];
  }
  __syncthreads();

  float* inv_lds = (float*)(lds + 69632);      // [256]
  {
    float s = ssq_part[t] + ssq_part[256 + t] + ssq_part[512 + t] + ssq_part[768 + t];
    inv_lds[t] = 1.0f / fmaxf(sqrtf(s), 1e-12f);
  }
  __syncthreads();

  // ---- softmax: 4 lanes per pixel over 81 window values (norm applied here) ----
  const int mrow = lane >> 2, s4 = lane & 3;
  const int myy = mrow >> 2, mxx = mrow & 3;
  const float* Srow = S + mrow * SSTR;
  float vals[21];
  float mx = -3.0e38f;
  #pragma unroll
  for (int i = 0; i < 21; ++i) {
    int j = s4 + 4 * i;
    if (j < 81) {
      int dy = j / 9, dx = j % 9;
      int qw = (wy * 4 + myy + dy) * 16 + wx * 4 + mxx + dx;
      float val = Srow[(myy + dy) * 12 + (mxx + dx)] * inv_lds[qw];
      vals[i] = val;
      mx = fmaxf(mx, val);
    }
  }
  mx = fmaxf(mx, __shfl_xor(mx, 1));
  mx = fmaxf(mx, __shfl_xor(mx, 2));
  float sum = 0.f;
  #pragma unroll
  for (int i = 0; i < 21; ++i) {
    int j = s4 + 4 * i;
    if (j < 81) { float e = __expf(vals[i] - mx); vals[i] = e; sum += e; }
  }
  sum += __shfl_xor(sum, 1);
  sum += __shfl_xor(sum, 2);
  float rs = 1.0f / sum;

  // ---- stage probs to LDS [64][81], then fully-coalesced float4 row copies ----
  float* probs = (float*)(lds + 38912);        // 64*81*4 = 20736 B
  const int pxid = (wy * 4 + myy) * 8 + (wx * 4 + mxx);
  #pragma unroll
  for (int i = 0; i < 21; ++i) {
    int j = s4 + 4 * i;
    if (j < 81) probs[pxid * 81 + j] = vals[i] * rs;
  }
  __syncthreads();
  if (t < 162) {
    #pragma unroll
    for (int r = 0; r < 8; ++r) {
      f32x4 d = *(const f32x4*)(probs + r * 648 + t * 4);
      *(f32x4*)(out + ((size_t)bz * NPIX + (size_t)(by * 8 + r) * HW + bx * 8) * 81 + t * 4) = d;
    }
  }
#undef ISSUE
#undef STAGEW
}

extern "C" void kernel_launch(void* const* d_in, const int* in_sizes, int n_in,
                              void* d_out, int out_size, void* d_ws, size_t ws_size,
                              hipStream_t stream) {
  const float* ft = (const float*)d_in[0];
  const float* fr = (const float*)d_in[1];
  float* out = (float*)d_out;

  unsigned short* T = (unsigned short*)d_ws;                    // 16 MB bf16 tar
  float* zp = (float*)((char*)d_ws + (size_t)NPIX * CDEP * 2);  // 1 KB zero page

  k_norm_tar<<<dim3(NPIX / 4), dim3(256), 0, stream>>>(ft, T, zp);
  k_fused<<<dim3(2048), dim3(256), 0, stream>>>(T, fr, zp, out);
}

// Round 8
// 187.964 us; speedup vs baseline: 3.8929x; 1.0598x over previous
//
#include <hip/hip_runtime.h>
#include <hip/hip_bf16.h>

#define HW 128
#define NPIX 16384          // 128*128
#define CDEP 512
#define NB 8

typedef __attribute__((ext_vector_type(8))) short short8;
typedef __attribute__((ext_vector_type(8))) __bf16 bf16x8;
typedef __attribute__((ext_vector_type(4))) float f32x4;
typedef __attribute__((ext_vector_type(4))) unsigned int u32x4;

static __device__ inline bf16x8 asbf(short8 v) {
  union { short8 s; bf16x8 b; } u; u.s = v; return u.b;
}
// round-to-nearest-even f32 -> bf16 bits
static __device__ inline unsigned short f2bf(float x) {
  unsigned u = __float_as_uint(x);
  return (unsigned short)((u + 0x7fffu + ((u >> 16) & 1u)) >> 16);
}
static __device__ inline unsigned pk2(float lo, float hi) {
  return (unsigned)f2bf(lo) | ((unsigned)f2bf(hi) << 16);
}

// ---------------- tar normalize: [16384,512] f32 -> bf16 [p,C]; also zero the zero-page ----
__global__ __launch_bounds__(256) void k_norm_tar(const float* __restrict__ ft,
                                                  unsigned short* __restrict__ T,
                                                  float* __restrict__ zp) {
  if (blockIdx.x == 0 && threadIdx.x < 64)
    ((f32x4*)zp)[threadIdx.x] = (f32x4){0.f, 0.f, 0.f, 0.f};
  int wave = threadIdx.x >> 6, lane = threadIdx.x & 63;
  int p = blockIdx.x * 4 + wave;
  const float* row = ft + (size_t)p * CDEP + lane * 8;
  float4 v0 = *(const float4*)(row);
  float4 v1 = *(const float4*)(row + 4);
  float s = v0.x*v0.x + v0.y*v0.y + v0.z*v0.z + v0.w*v0.w
          + v1.x*v1.x + v1.y*v1.y + v1.z*v1.z + v1.w*v1.w;
  #pragma unroll
  for (int off = 1; off < 64; off <<= 1) s += __shfl_xor(s, off);
  float sc = 1.0f / fmaxf(sqrtf(s), 1e-12f);
  float vv[8] = {v0.x, v0.y, v0.z, v0.w, v1.x, v1.y, v1.z, v1.w};
  short8 pkv;
  #pragma unroll
  for (int i = 0; i < 8; ++i) pkv[i] = (short)f2bf(vv[i] * sc);
  *(short8*)(T + (size_t)p * CDEP + lane * 8) = pkv;
}

// -------- fully fused: raw f32 refs -> bf16 LDS staging -> MFMA -> invnorm -> softmax --------
// grid 2048 (XCD=batch swizzle); block 256 = 4 waves; WG: 8x8 out px, 16x16 q window.
// K = 512 in 8 chunks of 64 c; LDS layout with conflict-killing key:
//   key(q) = (q + 4*(q>>4)) & 7
//   byte(q, c') = buf + q*128 + (((c'>>3) ^ key)<<4) + (c'&7)*2
// (key applied symmetrically on write & read; bank-quad histogram uniform 2-way.)
__global__ __launch_bounds__(256, 2) void k_fused(const unsigned short* __restrict__ Tb,
                                                  const float* __restrict__ fr,
                                                  const float* __restrict__ zp,
                                                  float* __restrict__ out) {
  __shared__ __align__(16) unsigned char lds[65536];   // 2 x 32KB staging (FULL size!)
  // epilogue (staging dead): S [0,37888), probs [38912,59648),
  //                          ssq_part [59648,63744), inv [63744,64768).
  const int t = threadIdx.x, lane = t & 63, wave = t >> 6;
  const int lb = blockIdx.x;
  const int logical = (lb & 7) * 256 + (lb >> 3);     // bijective: XCD <-> batch
  const int bx = logical & 15, by = (logical >> 4) & 15, bz = logical >> 8;
  const int wy = wave >> 1, wx = wave & 1;
  const int mA = lane & 15, kg = lane >> 4;

  // ---- staging geometry ----
  const int sy = lane >> 2, sx4 = lane & 3;
  const int rot = (wave + sy) & 3;
  const int gy = by * 8 - 4 + sy;
  const int gx4 = bx * 8 - 4 + sx4 * 4;
  const bool valid = ((unsigned)gy < 128u) && ((unsigned)gx4 <= 124u);
  const float* base = valid ? (fr + (size_t)bz * CDEP * NPIX + gy * HW + gx4) : zp;
  const size_t cstep = valid ? (size_t)NPIX : 0;
  const float* basec = base + (size_t)rot * 16 * cstep;   // fold rot into base

  // write addrs: q = sy*16 + sx4*4 + j ; slot = rot*2 + si (si static)
  int waddr[4][2];
  #pragma unroll
  for (int j = 0; j < 4; ++j) {
    int q = sy * 16 + sx4 * 4 + j;
    int key = (q + ((q >> 4) << 2)) & 7;
    #pragma unroll
    for (int si = 0; si < 2; ++si)
      waddr[j][si] = q * 128 + (((rot * 2 + si) ^ key) << 4);
  }

  // ---- B-read offsets: byte = q*128 + ((kg^key)<<4), step flips bit6 ----
  int qoff[9];
  #pragma unroll
  for (int tt = 0; tt < 9; ++tt) {
    int idx = tt * 16 + mA;
    int q = (wy * 4 + idx / 12) * 16 + (wx * 4 + idx % 12);
    int key = (q + ((q >> 4) << 2)) & 7;
    qoff[tt] = q * 128 + ((kg ^ key) << 4);
  }

  // ---- A row pointer (fragments loaded per chunk; 1-ahead prefetch) ----
  const int py = by * 8 + wy * 4 + (mA >> 2), px = bx * 8 + wx * 4 + (mA & 3);
  const short* arow = (const short*)Tb + (size_t)(py * HW + px) * CDEP + kg * 8;

  f32x4 acc[9];
  #pragma unroll
  for (int tt = 0; tt < 9; ++tt) acc[tt] = (f32x4){0.f, 0.f, 0.f, 0.f};
  float sq[4] = {0.f, 0.f, 0.f, 0.f};
  f32x4 v[16];

#define ISSUE(CH) { \
  _Pragma("unroll") \
  for (int cc = 0; cc < 16; ++cc) \
    v[cc] = *(const f32x4*)(basec + (size_t)((CH) * 64 + cc) * cstep); }

#define STAGEW(BUFO) { \
  _Pragma("unroll") \
  for (int j = 0; j < 4; ++j) { \
    _Pragma("unroll") \
    for (int si = 0; si < 2; ++si) { \
      u32x4 d; \
      _Pragma("unroll") \
      for (int k = 0; k < 4; ++k) { \
        float lo = v[si*8 + 2*k][j], hi = v[si*8 + 2*k + 1][j]; \
        sq[j] += lo*lo + hi*hi; \
        d[k] = pk2(lo, hi); \
      } \
      *(u32x4*)(lds + (BUFO) + waddr[j][si]) = d; \
    } } }

  // ---- prologue: stage chunk 0 -> buf0 ----
  ISSUE(0);
  STAGEW(0);
  short8 a0c = *(const short8*)(arow);
  short8 a1c = *(const short8*)(arow + 32);
  __syncthreads();

  // ---- main loop: 8 chunks of 64 c, double-buffered ----
  #pragma unroll
  for (int ch = 0; ch < 8; ++ch) {
    short8 a0n, a1n;
    if (ch < 7) {
      ISSUE(ch + 1);                     // T14: 16 loads deep in flight
      a0n = *(const short8*)(arow + (ch + 1) * 64);
      a1n = *(const short8*)(arow + (ch + 1) * 64 + 32);
    }
    const int bufo = (ch & 1) << 15;
    __builtin_amdgcn_s_setprio(1);
    #pragma unroll
    for (int step = 0; step < 2; ++step) {
      bf16x8 af = asbf(step ? a1c : a0c);
      const int sx = step << 6;
      #pragma unroll
      for (int tt = 0; tt < 9; ++tt) {
        short8 bv = *(const short8*)(lds + bufo + (qoff[tt] ^ sx));
        acc[tt] = __builtin_amdgcn_mfma_f32_16x16x32_bf16(af, asbf(bv), acc[tt], 0, 0, 0);
      }
    }
    __builtin_amdgcn_s_setprio(0);
    if (ch < 7) {
      const int nbufo = ((ch + 1) & 1) << 15;
      STAGEW(nbufo);
      a0c = a0n; a1c = a1n;
    }
    __syncthreads();
  }

  // ---- epilogue: ssq partials + S spill + invnorm ----
  float* ssq_part = (float*)(lds + 59648);     // [4][256]
  #pragma unroll
  for (int j = 0; j < 4; ++j)
    ssq_part[wave * 256 + sy * 16 + sx4 * 4 + j] = sq[j];

  const int SSTR = 148;
  float* S = (float*)lds + wave * 16 * SSTR;   // 4 x 16 x 148 x 4B = 37888 B
  #pragma unroll
  for (int tt = 0; tt < 9; ++tt) {
    #pragma unroll
    for (int r = 0; r < 4; ++r)
      S[(kg * 4 + r) * SSTR + tt * 16 + mA] = acc[tt][r];
  }
  __syncthreads();

  float* inv_lds = (float*)(lds + 63744);      // [256]
  {
    float s = ssq_part[t] + ssq_part[256 + t] + ssq_part[512 + t] + ssq_part[768 + t];
    inv_lds[t] = 1.0f / fmaxf(sqrtf(s), 1e-12f);
  }
  __syncthreads();

  // ---- softmax: 4 lanes per pixel over 81 window values (norm applied here) ----
  const int mrow = lane >> 2, s4 = lane & 3;
  const int myy = mrow >> 2, mxx = mrow & 3;
  const float* Srow = S + mrow * SSTR;
  float vals[21];
  float mx = -3.0e38f;
  #pragma unroll
  for (int i = 0; i < 21; ++i) {
    int j = s4 + 4 * i;
    if (j < 81) {
      int dy = j / 9, dx = j % 9;
      int qw = (wy * 4 + myy + dy) * 16 + wx * 4 + mxx + dx;
      float val = Srow[(myy + dy) * 12 + (mxx + dx)] * inv_lds[qw];
      vals[i] = val;
      mx = fmaxf(mx, val);
    }
  }
  mx = fmaxf(mx, __shfl_xor(mx, 1));
  mx = fmaxf(mx, __shfl_xor(mx, 2));
  float sum = 0.f;
  #pragma unroll
  for (int i = 0; i < 21; ++i) {
    int j = s4 + 4 * i;
    if (j < 81) { float e = __expf(vals[i] - mx); vals[i] = e; sum += e; }
  }
  sum += __shfl_xor(sum, 1);
  sum += __shfl_xor(sum, 2);
  float rs = 1.0f / sum;

  // ---- stage probs to LDS [64][81], then fully-coalesced float4 row copies ----
  float* probs = (float*)(lds + 38912);        // 64*81*4 = 20736 B
  const int pxid = (wy * 4 + myy) * 8 + (wx * 4 + mxx);
  #pragma unroll
  for (int i = 0; i < 21; ++i) {
    int j = s4 + 4 * i;
    if (j < 81) probs[pxid * 81 + j] = vals[i] * rs;
  }
  __syncthreads();
  if (t < 162) {
    #pragma unroll
    for (int r = 0; r < 8; ++r) {
      f32x4 d = *(const f32x4*)(probs + r * 648 + t * 4);
      *(f32x4*)(out + ((size_t)bz * NPIX + (size_t)(by * 8 + r) * HW + bx * 8) * 81 + t * 4) = d;
    }
  }
#undef ISSUE
#undef STAGEW
}

extern "C" void kernel_launch(void* const* d_in, const int* in_sizes, int n_in,
                              void* d_out, int out_size, void* d_ws, size_t ws_size,
                              hipStream_t stream) {
  const float* ft = (const float*)d_in[0];
  const float* fr = (const float*)d_in[1];
  float* out = (float*)d_out;

  unsigned short* T = (unsigned short*)d_ws;                    // 16 MB bf16 tar
  float* zp = (float*)((char*)d_ws + (size_t)NPIX * CDEP * 2);  // 1 KB zero page

  k_norm_tar<<<dim3(NPIX / 4), dim3(256), 0, stream>>>(ft, T, zp);
  k_fused<<<dim3(2048), dim3(256), 0, stream>>>(T, fr, zp, out);
}

// Round 9
// 185.772 us; speedup vs baseline: 3.9389x; 1.0118x over previous
//
#include <hip/hip_runtime.h>
#include <hip/hip_bf16.h>

#define HW 128
#define NPIX 16384          // 128*128
#define CDEP 512
#define NB 8

typedef __attribute__((ext_vector_type(8))) short short8;
typedef __attribute__((ext_vector_type(8))) __bf16 bf16x8;
typedef __attribute__((ext_vector_type(4))) float f32x4;
typedef __attribute__((ext_vector_type(4))) unsigned int u32x4;

static __device__ inline bf16x8 asbf(short8 v) {
  union { short8 s; bf16x8 b; } u; u.s = v; return u.b;
}
// round-to-nearest-even f32 -> bf16 bits (manual; cold path only)
static __device__ inline unsigned short f2bf(float x) {
  unsigned u = __float_as_uint(x);
  return (unsigned short)((u + 0x7fffu + ((u >> 16) & 1u)) >> 16);
}
// native RNE casts; compiler emits v_cvt (m240: faster than hand-rolled)
static __device__ inline unsigned pk2(float lo, float hi) {
  union { struct { __bf16 l, h; } p; unsigned u; } x;
  x.p.l = (__bf16)lo; x.p.h = (__bf16)hi;
  return x.u;
}

// ---------------- tar normalize: [16384,512] f32 -> bf16 [p,C]; also zero the zero-page ----
__global__ __launch_bounds__(256) void k_norm_tar(const float* __restrict__ ft,
                                                  unsigned short* __restrict__ T,
                                                  float* __restrict__ zp) {
  if (blockIdx.x == 0 && threadIdx.x < 64)
    ((f32x4*)zp)[threadIdx.x] = (f32x4){0.f, 0.f, 0.f, 0.f};
  int wave = threadIdx.x >> 6, lane = threadIdx.x & 63;
  int p = blockIdx.x * 4 + wave;
  const float* row = ft + (size_t)p * CDEP + lane * 8;
  float4 v0 = *(const float4*)(row);
  float4 v1 = *(const float4*)(row + 4);
  float s = v0.x*v0.x + v0.y*v0.y + v0.z*v0.z + v0.w*v0.w
          + v1.x*v1.x + v1.y*v1.y + v1.z*v1.z + v1.w*v1.w;
  #pragma unroll
  for (int off = 1; off < 64; off <<= 1) s += __shfl_xor(s, off);
  float sc = 1.0f / fmaxf(sqrtf(s), 1e-12f);
  float vv[8] = {v0.x, v0.y, v0.z, v0.w, v1.x, v1.y, v1.z, v1.w};
  short8 pkv;
  #pragma unroll
  for (int i = 0; i < 8; ++i) pkv[i] = (short)f2bf(vv[i] * sc);
  *(short8*)(T + (size_t)p * CDEP + lane * 8) = pkv;
}

// -------- fully fused: raw f32 refs -> bf16 LDS staging -> MFMA -> invnorm -> softmax --------
// grid 2048 (XCD=batch swizzle); block 256 = 4 waves; WG: 8x8 out px, 16x16 q window.
// K = 512 in 8 chunks of 64 c; LDS layout key(q) = (q + 4*(q>>4)) & 7:
//   byte(q, c') = buf + q*128 + (((c'>>3) ^ key)<<4) + (c'&7)*2
// sched_barrier(0) after ISSUE pins all staging loads BEFORE the MFMA cluster
// so they stay in flight together (defeats min-pressure load sinking).
__global__ __launch_bounds__(256, 2) void k_fused(const unsigned short* __restrict__ Tb,
                                                  const float* __restrict__ fr,
                                                  const float* __restrict__ zp,
                                                  float* __restrict__ out) {
  __shared__ __align__(16) unsigned char lds[65536];   // 2 x 32KB staging
  // epilogue (staging dead): S [0,37888), probs [38912,59648),
  //                          ssq_part [59648,63744), inv [63744,64768).
  const int t = threadIdx.x, lane = t & 63, wave = t >> 6;
  const int lb = blockIdx.x;
  const int logical = (lb & 7) * 256 + (lb >> 3);     // bijective: XCD <-> batch
  const int bx = logical & 15, by = (logical >> 4) & 15, bz = logical >> 8;
  const int wy = wave >> 1, wx = wave & 1;
  const int mA = lane & 15, kg = lane >> 4;

  // ---- staging geometry ----
  const int sy = lane >> 2, sx4 = lane & 3;
  const int rot = (wave + sy) & 3;
  const int gy = by * 8 - 4 + sy;
  const int gx4 = bx * 8 - 4 + sx4 * 4;
  const bool valid = ((unsigned)gy < 128u) && ((unsigned)gx4 <= 124u);
  const float* base = valid ? (fr + (size_t)bz * CDEP * NPIX + gy * HW + gx4) : zp;
  const size_t cstep = valid ? (size_t)NPIX : 0;
  const float* basec = base + (size_t)rot * 16 * cstep;   // fold rot into base

  // write addrs: q = sy*16 + sx4*4 + j ; slot = rot*2 + si (si static)
  int waddr[4][2];
  #pragma unroll
  for (int j = 0; j < 4; ++j) {
    int q = sy * 16 + sx4 * 4 + j;
    int key = (q + ((q >> 4) << 2)) & 7;
    #pragma unroll
    for (int si = 0; si < 2; ++si)
      waddr[j][si] = q * 128 + (((rot * 2 + si) ^ key) << 4);
  }

  // ---- B-read offsets: byte = q*128 + ((kg^key)<<4), step flips bit6 ----
  int qoff[9];
  #pragma unroll
  for (int tt = 0; tt < 9; ++tt) {
    int idx = tt * 16 + mA;
    int q = (wy * 4 + idx / 12) * 16 + (wx * 4 + idx % 12);
    int key = (q + ((q >> 4) << 2)) & 7;
    qoff[tt] = q * 128 + ((kg ^ key) << 4);
  }

  // ---- A row pointer (fragments loaded per chunk; 1-ahead prefetch) ----
  const int py = by * 8 + wy * 4 + (mA >> 2), px = bx * 8 + wx * 4 + (mA & 3);
  const short* arow = (const short*)Tb + (size_t)(py * HW + px) * CDEP + kg * 8;

  f32x4 acc[9];
  #pragma unroll
  for (int tt = 0; tt < 9; ++tt) acc[tt] = (f32x4){0.f, 0.f, 0.f, 0.f};
  float sq[4] = {0.f, 0.f, 0.f, 0.f};
  f32x4 v[16];

#define ISSUE(CH) { \
  _Pragma("unroll") \
  for (int cc = 0; cc < 16; ++cc) \
    v[cc] = *(const f32x4*)(basec + (size_t)((CH) * 64 + cc) * cstep); }

#define STAGEW(BUFO) { \
  _Pragma("unroll") \
  for (int j = 0; j < 4; ++j) { \
    _Pragma("unroll") \
    for (int si = 0; si < 2; ++si) { \
      u32x4 d; \
      _Pragma("unroll") \
      for (int k = 0; k < 4; ++k) { \
        float lo = v[si*8 + 2*k][j], hi = v[si*8 + 2*k + 1][j]; \
        sq[j] += lo*lo + hi*hi; \
        d[k] = pk2(lo, hi); \
      } \
      *(u32x4*)(lds + (BUFO) + waddr[j][si]) = d; \
    } } }

  // ---- prologue: stage chunk 0 -> buf0 ----
  ISSUE(0);
  STAGEW(0);
  short8 a0c = *(const short8*)(arow);
  short8 a1c = *(const short8*)(arow + 32);
  __syncthreads();

  // ---- main loop: 8 chunks of 64 c, double-buffered ----
  #pragma unroll
  for (int ch = 0; ch < 8; ++ch) {
    short8 a0n, a1n;
    if (ch < 7) {
      ISSUE(ch + 1);                     // T14: issue all 16 loads...
      a0n = *(const short8*)(arow + (ch + 1) * 64);
      a1n = *(const short8*)(arow + (ch + 1) * 64 + 32);
      __builtin_amdgcn_sched_barrier(0); // ...and PIN them above the MFMA phase
    }
    const int bufo = (ch & 1) << 15;
    __builtin_amdgcn_s_setprio(1);
    #pragma unroll
    for (int step = 0; step < 2; ++step) {
      bf16x8 af = asbf(step ? a1c : a0c);
      const int sx = step << 6;
      #pragma unroll
      for (int tt = 0; tt < 9; ++tt) {
        short8 bv = *(const short8*)(lds + bufo + (qoff[tt] ^ sx));
        acc[tt] = __builtin_amdgcn_mfma_f32_16x16x32_bf16(af, asbf(bv), acc[tt], 0, 0, 0);
      }
    }
    __builtin_amdgcn_s_setprio(0);
    if (ch < 7) {
      const int nbufo = ((ch + 1) & 1) << 15;
      STAGEW(nbufo);
      a0c = a0n; a1c = a1n;
    }
    __syncthreads();
  }

  // ---- epilogue: ssq partials + S spill + invnorm ----
  float* ssq_part = (float*)(lds + 59648);     // [4][256]
  #pragma unroll
  for (int j = 0; j < 4; ++j)
    ssq_part[wave * 256 + sy * 16 + sx4 * 4 + j] = sq[j];

  const int SSTR = 148;
  float* S = (float*)lds + wave * 16 * SSTR;   // 4 x 16 x 148 x 4B = 37888 B
  #pragma unroll
  for (int tt = 0; tt < 9; ++tt) {
    #pragma unroll
    for (int r = 0; r < 4; ++r)
      S[(kg * 4 + r) * SSTR + tt * 16 + mA] = acc[tt][r];
  }
  __syncthreads();

  float* inv_lds = (float*)(lds + 63744);      // [256]
  {
    float s = ssq_part[t] + ssq_part[256 + t] + ssq_part[512 + t] + ssq_part[768 + t];
    inv_lds[t] = 1.0f / fmaxf(sqrtf(s), 1e-12f);
  }
  __syncthreads();

  // ---- softmax: 4 lanes per pixel over 81 window values (norm applied here) ----
  const int mrow = lane >> 2, s4 = lane & 3;
  const int myy = mrow >> 2, mxx = mrow & 3;
  const float* Srow = S + mrow * SSTR;
  float vals[21];
  float mx = -3.0e38f;
  #pragma unroll
  for (int i = 0; i < 21; ++i) {
    int j = s4 + 4 * i;
    if (j < 81) {
      int dy = j / 9, dx = j % 9;
      int qw = (wy * 4 + myy + dy) * 16 + wx * 4 + mxx + dx;
      float val = Srow[(myy + dy) * 12 + (mxx + dx)] * inv_lds[qw];
      vals[i] = val;
      mx = fmaxf(mx, val);
    }
  }
  mx = fmaxf(mx, __shfl_xor(mx, 1));
  mx = fmaxf(mx, __shfl_xor(mx, 2));
  float sum = 0.f;
  #pragma unroll
  for (int i = 0; i < 21; ++i) {
    int j = s4 + 4 * i;
    if (j < 81) { float e = __expf(vals[i] - mx); vals[i] = e; sum += e; }
  }
  sum += __shfl_xor(sum, 1);
  sum += __shfl_xor(sum, 2);
  float rs = 1.0f / sum;

  // ---- stage probs to LDS [64][81], then fully-coalesced float4 row copies ----
  float* probs = (float*)(lds + 38912);        // 64*81*4 = 20736 B
  const int pxid = (wy * 4 + myy) * 8 + (wx * 4 + mxx);
  #pragma unroll
  for (int i = 0; i < 21; ++i) {
    int j = s4 + 4 * i;
    if (j < 81) probs[pxid * 81 + j] = vals[i] * rs;
  }
  __syncthreads();
  if (t < 162) {
    #pragma unroll
    for (int r = 0; r < 8; ++r) {
      f32x4 d = *(const f32x4*)(probs + r * 648 + t * 4);
      *(f32x4*)(out + ((size_t)bz * NPIX + (size_t)(by * 8 + r) * HW + bx * 8) * 81 + t * 4) = d;
    }
  }
#undef ISSUE
#undef STAGEW
}

extern "C" void kernel_launch(void* const* d_in, const int* in_sizes, int n_in,
                              void* d_out, int out_size, void* d_ws, size_t ws_size,
                              hipStream_t stream) {
  const float* ft = (const float*)d_in[0];
  const float* fr = (const float*)d_in[1];
  float* out = (float*)d_out;

  unsigned short* T = (unsigned short*)d_ws;                    // 16 MB bf16 tar
  float* zp = (float*)((char*)d_ws + (size_t)NPIX * CDEP * 2);  // 1 KB zero page

  k_norm_tar<<<dim3(NPIX / 4), dim3(256), 0, stream>>>(ft, T, zp);
  k_fused<<<dim3(2048), dim3(256), 0, stream>>>(T, fr, zp, out);
}